// Round 1
// baseline (303.926 us; speedup 1.0000x reference)
//
#include <hip/hip_runtime.h>

// Reference: result = items (4M x 2 x 2 x 3 fp32), final_pool = items[:1024].
// Pure D2D copy: out[0 : 48e6) = in[0 : 48e6); out[48e6 : 48e6+12288) = in[0 : 12288).
// Memory-bound: ~384 MB total traffic -> ~61 us at 6.3 TB/s.

// float4-granular: 48,000,000 / 4 = 12,000,000 main vecs; 12,288 / 4 = 3,072 tail vecs.
#define N_MAIN_VEC 12000000
#define N_TAIL_VEC 3072

__global__ __launch_bounds__(256) void copy_kernel(const float4* __restrict__ in,
                                                   float4* __restrict__ out) {
    long long i = (long long)blockIdx.x * blockDim.x + threadIdx.x;
    long long total = N_MAIN_VEC + N_TAIL_VEC;
    if (i >= total) return;
    if (i < N_MAIN_VEC) {
        out[i] = in[i];
    } else {
        out[i] = in[i - N_MAIN_VEC];  // tail re-reads first 3072 vecs (L2-hot)
    }
}

extern "C" void kernel_launch(void* const* d_in, const int* in_sizes, int n_in,
                              void* d_out, int out_size, void* d_ws, size_t ws_size,
                              hipStream_t stream) {
    const float4* in = (const float4*)d_in[0];
    float4* out = (float4*)d_out;
    long long total = N_MAIN_VEC + N_TAIL_VEC;
    int block = 256;
    long long grid = (total + block - 1) / block;
    copy_kernel<<<dim3((unsigned)grid), dim3(block), 0, stream>>>(in, out);
}